// Round 17
// baseline (491.113 us; speedup 1.0000x reference)
//
#include <hip/hip_runtime.h>
#include <math.h>

typedef __attribute__((ext_vector_type(8))) short short8;
typedef __attribute__((ext_vector_type(4))) float f32x4;

#define NCB 4
#define NE 1024
#define DIM 64
#define HW 16384
#define NPIX 131072
#define NWAVES 4096            // 1024 blocks * 4 waves
#define MSE_DENOM 8388608.0f   // NPIX*DIM
#define EPSF 1e-5f
#define WCB 6144               // bytes per 16-code chunk (3 splits * 16 codes * 128B)
#define NWC 64                 // chunks per codebook

__device__ __forceinline__ unsigned short f2bf(float x) {  // RNE fp32->bf16
    unsigned u = __float_as_uint(x);
    u += 0x7fffu + ((u >> 16) & 1u);
    return (unsigned short)(u >> 16);
}
__device__ __forceinline__ float bf2f(unsigned short h) {  // exact bf16->fp32
    return __uint_as_float(((unsigned)h) << 16);
}

// ------------- kernel 0: -0.5*||e||^2 per code (fp32, exact) -------------
__global__ __launch_bounds__(64) void rvq_norms(const float* __restrict__ cb,
                                                float* __restrict__ nrmh) {
    int code = blockIdx.x * 64 + threadIdx.x;  // 0..4095
    const float4* row = reinterpret_cast<const float4*>(cb + (size_t)code * DIM);
    float s0 = 0.f, s1 = 0.f, s2 = 0.f, s3 = 0.f;
#pragma unroll
    for (int k = 0; k < 16; ++k) {
        float4 v = row[k];
        s0 = fmaf(v.x, v.x, s0); s1 = fmaf(v.y, v.y, s1);
        s2 = fmaf(v.z, v.z, s2); s3 = fmaf(v.w, v.w, s3);
    }
    nrmh[code] = -0.5f * ((s0 + s1) + (s2 + s3));
}

// ------------- kernel 0b: pre-split codebook -> swizzled bf16x3 image ----
// 16-code blobs: [cb i][chunk c(16 codes)] 6144B = 3 planes of 2048B,
// addr within plane = (j*128 + dg*32 + h*16) ^ ((j&7)<<4), j = code&15.
// Byte-identical to the main kernel's per-wave LDS chunk buffer.
__global__ __launch_bounds__(256) void rvq_presplit(const float* __restrict__ cb,
                                                    unsigned short* __restrict__ gB) {
    int blk = blockIdx.x;            // i*16 + c64
    int tid = threadIdx.x;
    int code64 = tid >> 2, dg = tid & 3;
    int c0 = (blk & 15) << 6;
    int i  = blk >> 4;
    int C  = c0 + code64;            // global code within codebook
    const float4* s4 = reinterpret_cast<const float4*>(
        cb + ((size_t)i * NE + C) * DIM + dg * 16);
    float v[16];
    {
        float4 q;
        q = s4[0]; v[0]=q.x; v[1]=q.y; v[2]=q.z; v[3]=q.w;
        q = s4[1]; v[4]=q.x; v[5]=q.y; v[6]=q.z; v[7]=q.w;
        q = s4[2]; v[8]=q.x; v[9]=q.y; v[10]=q.z; v[11]=q.w;
        q = s4[3]; v[12]=q.x; v[13]=q.y; v[14]=q.z; v[15]=q.w;
    }
    char* outc = reinterpret_cast<char*>(gB) + ((size_t)i * NWC + (C >> 4)) * WCB;
    int j = C & 15;
    int linbase = j * 128 + dg * 32;
    int sw = (j & 7) << 4;
#pragma unroll
    for (int h = 0; h < 2; ++h) {
        short8 p1, p2, p3;
#pragma unroll
        for (int e = 0; e < 8; ++e) {
            float t = v[h * 8 + e];
            unsigned short u1 = f2bf(t); t -= bf2f(u1);
            unsigned short u2 = f2bf(t); t -= bf2f(u2);
            unsigned short u3 = f2bf(t);
            p1[e] = (short)u1; p2[e] = (short)u2; p3[e] = (short)u3;
        }
        int a = (linbase + h * 16) ^ sw;
        *reinterpret_cast<short8*>(outc + a)        = p1;
        *reinterpret_cast<short8*>(outc + 2048 + a) = p2;
        *reinterpret_cast<short8*>(outc + 4096 + a) = p3;
    }
}

// async 16B/lane global->LDS: wave-uniform LDS base, per-lane global src.
__device__ __forceinline__ void gload16(const void* gsrc, void* ldst) {
    __builtin_amdgcn_global_load_lds(
        (const __attribute__((address_space(1))) unsigned int*)gsrc,
        (__attribute__((address_space(3))) unsigned int*)ldst, 16, 0, 0);
}

// ------------- kernel 1: MFMA RVQ, M=32, BARRIER-FREE per-wave staging ---
// 1024 blocks x 4 waves, (256,2). R14's plateau (382us, MfmaUtil 45%) is
// 64 lockstep barriers x ~1.7k cyc + correlated stall phases across the 8
// resident waves/CU (R15: 2x barriers = +47us). This version removes ALL
// barriers: each wave owns a private 2x6KB LDS double buffer and stages
// its own 16-code chunks (global_load_lds + per-wave counted vmcnt(6) —
// exact, since vmcnt is per-wave and NO other VMEM op exists inside the
// scan loop: nh norms come from a per-wave 4KB LDS table staged per cb).
// 8 fully-decorrelated waves/CU -> cross-wave MFMA/VALU/LDS overlap
// (m114). Costs 4x L2 image re-read (~19 TB/s << 34.5 ceiling) + 16KB
// LDS. Compute body/MFMA order/scan byte-identical to validated R14.
// Safety: all LDS buffers are wave-private; stage(c+2) aliases
// compute(c)'s buffer but is separated by the MFMA cluster's lgkm-waited
// consumption + the iter-c+1 vmcnt fence (LLVM keeps may-aliasing
// store-after-load order; HW write lands >=150cyc after issue).
__global__ __launch_bounds__(256, 2) void rvq_main(
    const float* __restrict__ z, const unsigned short* __restrict__ gB,
    const float* __restrict__ nrmh, const float* __restrict__ cb,
    float* __restrict__ out_zq, float* __restrict__ out_idx,
    unsigned* __restrict__ hist, float* __restrict__ msePartial)
{
    __shared__ char  sW[4 * 2 * WCB];    // 48 KB: per-wave chunk double buffers
    __shared__ float sNh[4][NE];         // 16 KB: per-wave norm tables
    __shared__ int   sBest[4][32];

    const int tid  = threadIdx.x;
    const int lane = tid & 63;
    const int wid  = tid >> 6;
    const int col  = lane & 15;   // A-row within tile / D-col (code)
    const int g    = lane >> 4;   // k-group (8 dims) / D row-group
    const int blockPix = blockIdx.x * 128;
    char* myBuf = sW + wid * (2 * WCB);
    char* myNh  = reinterpret_cast<char*>(&sNh[wid][0]);
    const int sw = (col & 7) << 4;
    const char* gBb = reinterpret_cast<const char*>(gB);

    // cb0: issue nh table + chunk0 before anything (z-load+split covers)
#pragma unroll
    for (int k = 0; k < 4; ++k)
        gload16(reinterpret_cast<const char*>(nrmh) + k * 1024 + lane * 16,
                myNh + k * 1024 + lane * 16);
#pragma unroll
    for (int k = 0; k < 6; ++k)
        gload16(gBb + k * 1024 + lane * 16, myBuf + k * 1024 + lane * 16);

    size_t zb[2];
#pragma unroll
    for (int m = 0; m < 2; ++m) {
        int pf = blockPix + wid * 32 + m * 16 + col;
        zb[m] = (size_t)(pf >> 14) * 1048576 + (size_t)(pf & 16383);
    }

    float r[2][2][8];   // [m][kh][e], dim = kh*32 + g*8 + e
#pragma unroll
    for (int m = 0; m < 2; ++m)
#pragma unroll
        for (int kh = 0; kh < 2; ++kh)
#pragma unroll
            for (int e = 0; e < 8; ++e)
                r[m][kh][e] = z[zb[m] + (size_t)(kh * 32 + g * 8 + e) * HW];

    for (int i = 0; i < NCB; ++i) {
        const char* gBi = gBb + (size_t)i * NWC * WCB;

        // bf16x3 split of r -> A-frags (once per codebook; covers staging)
        short8 A[3][2][2];
#pragma unroll
        for (int m = 0; m < 2; ++m)
#pragma unroll
            for (int kh = 0; kh < 2; ++kh)
#pragma unroll
                for (int e = 0; e < 8; ++e) {
                    float t = r[m][kh][e];
                    unsigned short u1 = f2bf(t); t -= bf2f(u1);
                    unsigned short u2 = f2bf(t); t -= bf2f(u2);
                    unsigned short u3 = f2bf(t);
                    A[0][m][kh][e] = (short)u1;
                    A[1][m][kh][e] = (short)u2;
                    A[2][m][kh][e] = (short)u3;
                }

        float maxv[2][4]; int maxi[2][4];
#pragma unroll
        for (int m = 0; m < 2; ++m)
#pragma unroll
            for (int rr = 0; rr < 4; ++rr) { maxv[m][rr] = -3.4e38f; maxi[m][rr] = 0; }

        for (int c = 0; c < NWC; ++c) {
            if (c < NWC - 1) {   // stage next chunk into the other buffer
                const char* gc = gBi + (size_t)(c + 1) * WCB;
                char* dst = myBuf + ((c + 1) & 1) * WCB;
#pragma unroll
                for (int k = 0; k < 6; ++k)
                    gload16(gc + k * 1024 + lane * 16, dst + k * 1024 + lane * 16);
                // own 6 newest = chunk c+1; everything older (chunk c, nh
                // table, prior-cb epilogue VMEM) is complete after this:
                asm volatile("s_waitcnt vmcnt(6)" ::: "memory");
            } else {
                asm volatile("s_waitcnt vmcnt(0)" ::: "memory");
            }
            const char* sbc = myBuf + (c & 1) * WCB;

            const int code = col;                 // 16-code chunk: code = col
            float nh = sNh[wid][(c << 4) + col];  // LDS broadcast, no VMEM
            f32x4 acc[2];
#pragma unroll
            for (int rr = 0; rr < 4; ++rr) { acc[0][rr] = nh; acc[1][rr] = nh; }

            __builtin_amdgcn_s_setprio(1);
#pragma unroll
            for (int sb = 0; sb < 3; ++sb) {   // B-split-major: 2 B regs live
                short8 B0 = *reinterpret_cast<const short8*>(
                    sbc + sb * 2048 + ((((code << 7) + (g << 4))) ^ sw));
                short8 B1 = *reinterpret_cast<const short8*>(
                    sbc + sb * 2048 + ((((code << 7) + 64 + (g << 4))) ^ sw));
#pragma unroll
                for (int sa = 0; sa < 3 - sb; ++sa) {   // products with sa+sb<=2
                    acc[0] = __builtin_amdgcn_mfma_f32_16x16x32_bf16(A[sa][0][0], B0, acc[0], 0, 0, 0);
                    acc[1] = __builtin_amdgcn_mfma_f32_16x16x32_bf16(A[sa][1][0], B0, acc[1], 0, 0, 0);
                    acc[0] = __builtin_amdgcn_mfma_f32_16x16x32_bf16(A[sa][0][1], B1, acc[0], 0, 0, 0);
                    acc[1] = __builtin_amdgcn_mfma_f32_16x16x32_bf16(A[sa][1][1], B1, acc[1], 0, 0, 0);
                }
            }
            __builtin_amdgcn_s_setprio(0);

#pragma unroll
            for (int m = 0; m < 2; ++m)
#pragma unroll
                for (int rr = 0; rr < 4; ++rr) {
                    float s = acc[m][rr];          // argmax s == argmin dist
                    if (s > maxv[m][rr]) { maxv[m][rr] = s; maxi[m][rr] = (c << 4) + code; }
                }
        }

        // next codebook's nh table + chunk0: issue NOW (epilogue covers).
        // Both targets' last readers were this wave's own chunk 62/63 —
        // program order, same wave: safe without any barrier.
        if (i < NCB - 1) {
            const char* nsrc = reinterpret_cast<const char*>(nrmh) + (size_t)(i + 1) * 4096;
#pragma unroll
            for (int k = 0; k < 4; ++k)
                gload16(nsrc + k * 1024 + lane * 16, myNh + k * 1024 + lane * 16);
            const char* gn = gBb + (size_t)(i + 1) * NWC * WCB;
#pragma unroll
            for (int k = 0; k < 6; ++k)
                gload16(gn + k * 1024 + lane * 16, myBuf + k * 1024 + lane * 16);
        }

        // cross-lane argmax within each 16-lane group, idx tie-break
#pragma unroll
        for (int m = 0; m < 2; ++m)
#pragma unroll
            for (int rr = 0; rr < 4; ++rr) {
                float v = maxv[m][rr]; int ix = maxi[m][rr];
#pragma unroll
                for (int off = 1; off < 16; off <<= 1) {
                    float ov = __shfl_xor(v, off, 64);
                    int   oi = __shfl_xor(ix, off, 64);
                    if (ov > v || (ov == v && oi < ix)) { v = ov; ix = oi; }
                }
                maxi[m][rr] = ix;
            }
        // wave-private exchange (same-wave LDS ordering; no barrier needed)
        if (col == 0) {
#pragma unroll
            for (int m = 0; m < 2; ++m)
#pragma unroll
                for (int rr = 0; rr < 4; ++rr)
                    sBest[wid][m * 16 + g * 4 + rr] = maxi[m][rr];
        }

        const float* cbi = cb + (size_t)i * NE * DIM;
        if (lane < 16) {  // idx output + histogram, one writer per row
#pragma unroll
            for (int m = 0; m < 2; ++m) {
                int pfr = blockPix + wid * 32 + m * 16 + lane;
                int bb = pfr >> 14, yy = (pfr >> 7) & 127, xx = pfr & 127;
                int bi = sBest[wid][m * 16 + lane];
                size_t off = (size_t)bb * 65536 + (size_t)(yy >> 2) * 2048
                           + (size_t)(xx >> 2) * 64
                           + (size_t)(((yy & 3) << 2) + (xx & 3)) * 4 + (size_t)i;
                out_idx[off] = (float)bi;
                atomicAdd(&hist[i * NE + bi], 1u);
            }
        }

        // residual update from ORIGINAL fp32 codebook (keeps r exact)
#pragma unroll
        for (int m = 0; m < 2; ++m) {
            const int best = sBest[wid][m * 16 + col];
            const float* er = cbi + (size_t)best * DIM;
#pragma unroll
            for (int kh = 0; kh < 2; ++kh) {
                const float4* e4 = reinterpret_cast<const float4*>(er + kh * 32 + g * 8);
                float4 q0 = e4[0], q1 = e4[1];
                r[m][kh][0] -= q0.x; r[m][kh][1] -= q0.y;
                r[m][kh][2] -= q0.z; r[m][kh][3] -= q0.w;
                r[m][kh][4] -= q1.x; r[m][kh][5] -= q1.y;
                r[m][kh][6] -= q1.z; r[m][kh][7] -= q1.w;
            }
        }

        // MSE partial: (z_q - r_old)^2 = r_new^2
        float s = 0.f;
#pragma unroll
        for (int m = 0; m < 2; ++m)
#pragma unroll
            for (int kh = 0; kh < 2; ++kh)
#pragma unroll
                for (int e = 0; e < 8; ++e) s = fmaf(r[m][kh][e], r[m][kh][e], s);
#pragma unroll
        for (int d_ = 32; d_ > 0; d_ >>= 1) s += __shfl_down(s, d_, 64);
        if (lane == 0) msePartial[i * NWAVES + blockIdx.x * 4 + wid] = s;
    }

    // epilogue: z_q = z - r_final (telescoped straight-through sum)
#pragma unroll
    for (int m = 0; m < 2; ++m)
#pragma unroll
        for (int kh = 0; kh < 2; ++kh)
#pragma unroll
            for (int e = 0; e < 8; ++e) {
                size_t o = zb[m] + (size_t)(kh * 32 + g * 8 + e) * HW;
                out_zq[o] = z[o] - r[m][kh][e];
            }
}

// ---------------- kernel 2: deterministic loss finalize ----------------
__global__ __launch_bounds__(1024) void rvq_finalize(
    const unsigned* __restrict__ hist, const float* __restrict__ msePartial,
    float* __restrict__ out_loss)
{
    __shared__ float red[1024];
    int t = threadIdx.x;
    float loss = 0.f;
    for (int i = 0; i < NCB; ++i) {
        float cnt = (float)hist[i * NE + t];
        float prob = (cnt + EPSF) / (131072.0f + EPSF * 1024.0f);
        red[t] = -prob * logf(prob + EPSF);
        __syncthreads();
        for (int s = 512; s > 0; s >>= 1) { if (t < s) red[t] += red[t + s]; __syncthreads(); }
        float entropy = red[0];
        __syncthreads();
        float acc = 0.f;
#pragma unroll
        for (int k = 0; k < 4; ++k) acc += msePartial[i * NWAVES + k * 1024 + t];
        red[t] = acc;
        __syncthreads();
        for (int s = 512; s > 0; s >>= 1) { if (t < s) red[t] += red[t + s]; __syncthreads(); }
        float mse_sum = red[0];
        __syncthreads();
        loss += 0.25f * (mse_sum / MSE_DENOM) + 0.01f * (logf(1024.0f) - entropy);
    }
    if (t == 0) out_loss[0] = loss;
}

extern "C" void kernel_launch(void* const* d_in, const int* in_sizes, int n_in,
                              void* d_out, int out_size, void* d_ws, size_t ws_size,
                              hipStream_t stream) {
    const float* z  = (const float*)d_in[0];
    const float* cb = (const float*)d_in[1];

    float* out      = (float*)d_out;
    float* out_zq   = out;                    // 8388608
    float* out_loss = out + 8388608;          // 1
    float* out_idx  = out + 8388609;          // 524288 (indices as float)

    unsigned* hist        = (unsigned*)d_ws;                         // 16 KB
    float*    nrmh        = (float*)((char*)d_ws + 16384);           // 16 KB
    float*    msePartial  = (float*)((char*)d_ws + 32768);           // 64 KB (4*4096 f32)
    unsigned short* gB    = (unsigned short*)((char*)d_ws + 163840); // 1.5 MB pre-split image

    hipMemsetAsync(d_ws, 0, 16384, stream);   // zero histogram (deterministic)
    rvq_norms<<<64, 64, 0, stream>>>(cb, nrmh);
    rvq_presplit<<<64, 256, 0, stream>>>(cb, gB);
    rvq_main<<<1024, 256, 0, stream>>>(z, gB, nrmh, cb, out_zq, out_idx, hist, msePartial);
    rvq_finalize<<<1, 1024, 0, stream>>>(hist, msePartial, out_loss);
}

// Round 18
// 398.794 us; speedup vs baseline: 1.2315x; 1.2315x over previous
//
#include <hip/hip_runtime.h>
#include <math.h>

typedef __attribute__((ext_vector_type(8))) short short8;
typedef __attribute__((ext_vector_type(4))) float f32x4;

#define NCB 4
#define NE 1024
#define DIM 64
#define HW 16384
#define NPIX 131072
#define NWAVES 4096            // 1024 blocks * 4 waves
#define MSE_DENOM 8388608.0f   // NPIX*DIM
#define EPSF 1e-5f
#define CHUNK_BYTES 24576      // 3 splits * 64 codes * 64 dims * 2B
#define CHUNK_SHORTS 12288
#define NCHUNK 16              // chunks per codebook

__device__ __forceinline__ unsigned short f2bf(float x) {  // RNE fp32->bf16
    unsigned u = __float_as_uint(x);
    u += 0x7fffu + ((u >> 16) & 1u);
    return (unsigned short)(u >> 16);
}
__device__ __forceinline__ float bf2f(unsigned short h) {  // exact bf16->fp32
    return __uint_as_float(((unsigned)h) << 16);
}

// ------------- kernel 0: -0.5*||e||^2 per code (fp32, exact) -------------
__global__ __launch_bounds__(64) void rvq_norms(const float* __restrict__ cb,
                                                float* __restrict__ nrmh) {
    int code = blockIdx.x * 64 + threadIdx.x;  // 0..4095
    const float4* row = reinterpret_cast<const float4*>(cb + (size_t)code * DIM);
    float s0 = 0.f, s1 = 0.f, s2 = 0.f, s3 = 0.f;
#pragma unroll
    for (int k = 0; k < 16; ++k) {
        float4 v = row[k];
        s0 = fmaf(v.x, v.x, s0); s1 = fmaf(v.y, v.y, s1);
        s2 = fmaf(v.z, v.z, s2); s3 = fmaf(v.w, v.w, s3);
    }
    nrmh[code] = -0.5f * ((s0 + s1) + (s2 + s3));
}

// ------------- kernel 0b: pre-split codebook -> swizzled bf16x3 image ----
// R5-validated layout: [cb i][chunk c(64 codes)] 24KB blobs, 3 planes of
// 8192B, addr=(code*128+dg*32+h*16)^((code&7)<<4). Byte-identical to the
// main kernel's LDS chunk buffer.
__global__ __launch_bounds__(256) void rvq_presplit(const float* __restrict__ cb,
                                                    unsigned short* __restrict__ gB) {
    int blk = blockIdx.x;            // i*16 + c
    int tid = threadIdx.x;
    int code = tid >> 2, dg = tid & 3;
    int c0 = (blk & 15) << 6;
    int i  = blk >> 4;
    const float4* s4 = reinterpret_cast<const float4*>(
        cb + ((size_t)i * NE + c0 + code) * DIM + dg * 16);
    float v[16];
    {
        float4 q;
        q = s4[0]; v[0]=q.x; v[1]=q.y; v[2]=q.z; v[3]=q.w;
        q = s4[1]; v[4]=q.x; v[5]=q.y; v[6]=q.z; v[7]=q.w;
        q = s4[2]; v[8]=q.x; v[9]=q.y; v[10]=q.z; v[11]=q.w;
        q = s4[3]; v[12]=q.x; v[13]=q.y; v[14]=q.z; v[15]=q.w;
    }
    char* outc = reinterpret_cast<char*>(gB + (size_t)blk * CHUNK_SHORTS);
    int linbase = code * 128 + dg * 32;
    int sw = (code & 7) << 4;
#pragma unroll
    for (int h = 0; h < 2; ++h) {
        short8 p1, p2, p3;
#pragma unroll
        for (int e = 0; e < 8; ++e) {
            float t = v[h * 8 + e];
            unsigned short u1 = f2bf(t); t -= bf2f(u1);
            unsigned short u2 = f2bf(t); t -= bf2f(u2);
            unsigned short u3 = f2bf(t);
            p1[e] = (short)u1; p2[e] = (short)u2; p3[e] = (short)u3;
        }
        int a = (linbase + h * 16) ^ sw;
        *reinterpret_cast<short8*>(outc + a)         = p1;
        *reinterpret_cast<short8*>(outc + 8192 + a)  = p2;
        *reinterpret_cast<short8*>(outc + 16384 + a) = p3;
    }
}

// async 16B/lane global->LDS: wave-uniform LDS base, per-lane global src.
__device__ __forceinline__ void gload16(const void* gsrc, void* ldst) {
    __builtin_amdgcn_global_load_lds(
        (const __attribute__((address_space(1))) unsigned int*)gsrc,
        (__attribute__((address_space(3))) unsigned int*)ldst, 16, 0, 0);
}

// ------------- kernel 1: MFMA RVQ, M=32, rotating B-pair prefetch --------
// 1024 blocks x 4 waves, (256,2) — R14 base (382us, MfmaUtil 45, VGPR 124,
// clean). Diagnosis of the 45% plateau (invariant across M/chunk/occup/
// barrier-style, R7/R9/R13/R14): each sb-group's [2 ds_read_b128 ->
// lgkm wait -> MFMA cluster] exposes a cold load-use latency gap 3x per
// sub (~180-360cyc vs ~466cyc MFMA). Fix: rotate a one-pair-ahead B
// prefetch (P live, N in flight) so the NEXT pair's ds_reads fly under
// the CURRENT pair's MFMAs, continuously across all 12 (sub,sb) pairs of
// a chunk (restart only at the chunk barrier). +8 VGPR only (R16's spill
// was preload-all-6 AND 6 chains = +32). Numerics bit-identical to R14.
__global__ __launch_bounds__(256, 2) void rvq_main(
    const float* __restrict__ z, const unsigned short* __restrict__ gB,
    const float* __restrict__ nrmh, const float* __restrict__ cb,
    float* __restrict__ out_zq, float* __restrict__ out_idx,
    unsigned* __restrict__ hist, float* __restrict__ msePartial)
{
    __shared__ uint4 sB[2][CHUNK_BYTES / 16];   // 48 KB double buffer
    __shared__ int   sBest[4][32];

    const int tid  = threadIdx.x;
    const int lane = tid & 63;
    const int wid  = tid >> 6;
    const int col  = lane & 15;   // A-row within tile / D-col (code)
    const int g    = lane >> 4;   // k-group (8 dims) / D row-group
    const int blockPix = blockIdx.x * 128;
    char* sBase = reinterpret_cast<char*>(sB);
    const int sw = (col & 7) << 4;

    // cb0 chunk0: issue before anything else (z-load+split covers latency)
#pragma unroll
    for (int k = 0; k < 6; ++k)
        gload16(reinterpret_cast<const char*>(gB) + k * 4096 + tid * 16,
                sBase + k * 4096 + tid * 16);

    size_t zb[2];
#pragma unroll
    for (int m = 0; m < 2; ++m) {
        int pf = blockPix + wid * 32 + m * 16 + col;
        zb[m] = (size_t)(pf >> 14) * 1048576 + (size_t)(pf & 16383);
    }

    float r[2][2][8];   // [m][kh][e], dim = kh*32 + g*8 + e
#pragma unroll
    for (int m = 0; m < 2; ++m)
#pragma unroll
        for (int kh = 0; kh < 2; ++kh)
#pragma unroll
            for (int e = 0; e < 8; ++e)
                r[m][kh][e] = z[zb[m] + (size_t)(kh * 32 + g * 8 + e) * HW];

    for (int i = 0; i < NCB; ++i) {
        const char* gBi = reinterpret_cast<const char*>(gB) + (size_t)i * NCHUNK * CHUNK_BYTES;
        const float* nrm_i = nrmh + i * NE;

        // bf16x3 split of r -> A-frags (once per codebook)
        short8 A[3][2][2];
#pragma unroll
        for (int m = 0; m < 2; ++m)
#pragma unroll
            for (int kh = 0; kh < 2; ++kh)
#pragma unroll
                for (int e = 0; e < 8; ++e) {
                    float t = r[m][kh][e];
                    unsigned short u1 = f2bf(t); t -= bf2f(u1);
                    unsigned short u2 = f2bf(t); t -= bf2f(u2);
                    unsigned short u3 = f2bf(t);
                    A[0][m][kh][e] = (short)u1;
                    A[1][m][kh][e] = (short)u2;
                    A[2][m][kh][e] = (short)u3;
                }

        float maxv[2][4]; int maxi[2][4];
#pragma unroll
        for (int m = 0; m < 2; ++m)
#pragma unroll
            for (int rr = 0; rr < 4; ++rr) { maxv[m][rr] = -3.4e38f; maxi[m][rr] = 0; }

        for (int c = 0; c < NCHUNK; ++c) {
            // drains own vmcnt (gloads(c) covered by compute(c-1)) + syncs:
            // after this, buf[c&1] is fully populated for ALL waves, and
            // buf[(c+1)&1]'s last readers (compute(c-1)) are all done.
            __syncthreads();
            if (c < NCHUNK - 1) {   // issue next chunk into the freed buffer
                const char* gc = gBi + (size_t)(c + 1) * CHUNK_BYTES;
                char* sbn = sBase + ((c + 1) & 1) * CHUNK_BYTES;
#pragma unroll
                for (int k = 0; k < 6; ++k)
                    gload16(gc + k * 4096 + tid * 16, sbn + k * 4096 + tid * 16);
            }
            const char* sbc = sBase + (c & 1) * CHUNK_BYTES;

            // rotating B-pair prefetch across the chunk's 12 (sub,sb) pairs
            short8 P0, P1, N0, N1;
#define BPTR(SBB, CODE, H) reinterpret_cast<const short8*>( \
            sbc + (SBB) * 8192 + (((((CODE) << 7) + (H) * 64 + (g << 4))) ^ sw))
#define MFMA_SB(SBB)                                                                   \
            _Pragma("unroll")                                                          \
            for (int sa = 0; sa < 3 - (SBB); ++sa) {                                   \
                accA = __builtin_amdgcn_mfma_f32_16x16x32_bf16(A[sa][0][0], P0, accA, 0, 0, 0); \
                accB = __builtin_amdgcn_mfma_f32_16x16x32_bf16(A[sa][1][0], P0, accB, 0, 0, 0); \
                accA = __builtin_amdgcn_mfma_f32_16x16x32_bf16(A[sa][0][1], P1, accA, 0, 0, 0); \
                accB = __builtin_amdgcn_mfma_f32_16x16x32_bf16(A[sa][1][1], P1, accB, 0, 0, 0); \
            }

            // prime: (sub0, sb0)
            P0 = *BPTR(0, col, 0); P1 = *BPTR(0, col, 1);

#pragma unroll
            for (int sub = 0; sub < 4; ++sub) {
                const int code = (sub << 4) + col;
                float nh = nrm_i[(c << 6) + code];
                f32x4 accA, accB;
#pragma unroll
                for (int rr = 0; rr < 4; ++rr) { accA[rr] = nh; accB[rr] = nh; }

                __builtin_amdgcn_s_setprio(1);
                // sb=0: prefetch sb=1, compute on P
                N0 = *BPTR(1, code, 0); N1 = *BPTR(1, code, 1);
                MFMA_SB(0)
                P0 = N0; P1 = N1;
                // sb=1: prefetch sb=2
                N0 = *BPTR(2, code, 0); N1 = *BPTR(2, code, 1);
                MFMA_SB(1)
                P0 = N0; P1 = N1;
                // sb=2: prefetch next sub's sb=0 (if any)
                if (sub < 3) { N0 = *BPTR(0, code + 16, 0); N1 = *BPTR(0, code + 16, 1); }
                MFMA_SB(2)
                if (sub < 3) { P0 = N0; P1 = N1; }
                __builtin_amdgcn_s_setprio(0);

#pragma unroll
                for (int rr = 0; rr < 4; ++rr) {
                    float s0 = accA[rr];           // argmax s == argmin dist
                    if (s0 > maxv[0][rr]) { maxv[0][rr] = s0; maxi[0][rr] = (c << 6) + code; }
                    float s1 = accB[rr];
                    if (s1 > maxv[1][rr]) { maxv[1][rr] = s1; maxi[1][rr] = (c << 6) + code; }
                }
            }
#undef BPTR
#undef MFMA_SB
        }

        // next codebook's chunk0: issue NOW so the epilogue covers latency.
        if (i < NCB - 1) {
            const char* gn = reinterpret_cast<const char*>(gB)
                           + (size_t)(i + 1) * NCHUNK * CHUNK_BYTES;
#pragma unroll
            for (int k = 0; k < 6; ++k)
                gload16(gn + k * 4096 + tid * 16, sBase + k * 4096 + tid * 16);
        }

        // cross-lane argmax within each 16-lane group, idx tie-break
#pragma unroll
        for (int m = 0; m < 2; ++m)
#pragma unroll
            for (int rr = 0; rr < 4; ++rr) {
                float v = maxv[m][rr]; int ix = maxi[m][rr];
#pragma unroll
                for (int off = 1; off < 16; off <<= 1) {
                    float ov = __shfl_xor(v, off, 64);
                    int   oi = __shfl_xor(ix, off, 64);
                    if (ov > v || (ov == v && oi < ix)) { v = ov; ix = oi; }
                }
                maxi[m][rr] = ix;
            }
        // wave-private exchange (same-wave LDS ordering; no barrier needed)
        if (col == 0) {
#pragma unroll
            for (int m = 0; m < 2; ++m)
#pragma unroll
                for (int rr = 0; rr < 4; ++rr)
                    sBest[wid][m * 16 + g * 4 + rr] = maxi[m][rr];
        }

        const float* cbi = cb + (size_t)i * NE * DIM;
        if (lane < 16) {  // idx output + histogram, one writer per row
#pragma unroll
            for (int m = 0; m < 2; ++m) {
                int pfr = blockPix + wid * 32 + m * 16 + lane;
                int bb = pfr >> 14, yy = (pfr >> 7) & 127, xx = pfr & 127;
                int bi = sBest[wid][m * 16 + lane];
                size_t off = (size_t)bb * 65536 + (size_t)(yy >> 2) * 2048
                           + (size_t)(xx >> 2) * 64
                           + (size_t)(((yy & 3) << 2) + (xx & 3)) * 4 + (size_t)i;
                out_idx[off] = (float)bi;
                atomicAdd(&hist[i * NE + bi], 1u);
            }
        }

        // residual update from ORIGINAL fp32 codebook (keeps r exact)
#pragma unroll
        for (int m = 0; m < 2; ++m) {
            const int best = sBest[wid][m * 16 + col];
            const float* er = cbi + (size_t)best * DIM;
#pragma unroll
            for (int kh = 0; kh < 2; ++kh) {
                const float4* e4 = reinterpret_cast<const float4*>(er + kh * 32 + g * 8);
                float4 q0 = e4[0], q1 = e4[1];
                r[m][kh][0] -= q0.x; r[m][kh][1] -= q0.y;
                r[m][kh][2] -= q0.z; r[m][kh][3] -= q0.w;
                r[m][kh][4] -= q1.x; r[m][kh][5] -= q1.y;
                r[m][kh][6] -= q1.z; r[m][kh][7] -= q1.w;
            }
        }

        // MSE partial: (z_q - r_old)^2 = r_new^2
        float s = 0.f;
#pragma unroll
        for (int m = 0; m < 2; ++m)
#pragma unroll
            for (int kh = 0; kh < 2; ++kh)
#pragma unroll
                for (int e = 0; e < 8; ++e) s = fmaf(r[m][kh][e], r[m][kh][e], s);
#pragma unroll
        for (int d_ = 32; d_ > 0; d_ >>= 1) s += __shfl_down(s, d_, 64);
        if (lane == 0) msePartial[i * NWAVES + blockIdx.x * 4 + wid] = s;
    }

    // epilogue: z_q = z - r_final (telescoped straight-through sum)
#pragma unroll
    for (int m = 0; m < 2; ++m)
#pragma unroll
        for (int kh = 0; kh < 2; ++kh)
#pragma unroll
            for (int e = 0; e < 8; ++e) {
                size_t o = zb[m] + (size_t)(kh * 32 + g * 8 + e) * HW;
                out_zq[o] = z[o] - r[m][kh][e];
            }
}

// ---------------- kernel 2: deterministic loss finalize ----------------
__global__ __launch_bounds__(1024) void rvq_finalize(
    const unsigned* __restrict__ hist, const float* __restrict__ msePartial,
    float* __restrict__ out_loss)
{
    __shared__ float red[1024];
    int t = threadIdx.x;
    float loss = 0.f;
    for (int i = 0; i < NCB; ++i) {
        float cnt = (float)hist[i * NE + t];
        float prob = (cnt + EPSF) / (131072.0f + EPSF * 1024.0f);
        red[t] = -prob * logf(prob + EPSF);
        __syncthreads();
        for (int s = 512; s > 0; s >>= 1) { if (t < s) red[t] += red[t + s]; __syncthreads(); }
        float entropy = red[0];
        __syncthreads();
        float acc = 0.f;
#pragma unroll
        for (int k = 0; k < 4; ++k) acc += msePartial[i * NWAVES + k * 1024 + t];
        red[t] = acc;
        __syncthreads();
        for (int s = 512; s > 0; s >>= 1) { if (t < s) red[t] += red[t + s]; __syncthreads(); }
        float mse_sum = red[0];
        __syncthreads();
        loss += 0.25f * (mse_sum / MSE_DENOM) + 0.01f * (logf(1024.0f) - entropy);
    }
    if (t == 0) out_loss[0] = loss;
}

extern "C" void kernel_launch(void* const* d_in, const int* in_sizes, int n_in,
                              void* d_out, int out_size, void* d_ws, size_t ws_size,
                              hipStream_t stream) {
    const float* z  = (const float*)d_in[0];
    const float* cb = (const float*)d_in[1];

    float* out      = (float*)d_out;
    float* out_zq   = out;                    // 8388608
    float* out_loss = out + 8388608;          // 1
    float* out_idx  = out + 8388609;          // 524288 (indices as float)

    unsigned* hist        = (unsigned*)d_ws;                         // 16 KB
    float*    nrmh        = (float*)((char*)d_ws + 16384);           // 16 KB
    float*    msePartial  = (float*)((char*)d_ws + 32768);           // 64 KB (4*4096 f32)
    unsigned short* gB    = (unsigned short*)((char*)d_ws + 163840); // 1.5 MB pre-split image

    hipMemsetAsync(d_ws, 0, 16384, stream);   // zero histogram (deterministic)
    rvq_norms<<<64, 64, 0, stream>>>(cb, nrmh);
    rvq_presplit<<<64, 256, 0, stream>>>(cb, gB);
    rvq_main<<<1024, 256, 0, stream>>>(z, gB, nrmh, cb, out_zq, out_idx, hist, msePartial);
    rvq_finalize<<<1, 1024, 0, stream>>>(hist, msePartial, out_loss);
}